// Round 9
// baseline (720.436 us; speedup 1.0000x reference)
//
#include <hip/hip_runtime.h>
#include <hip/hip_bf16.h>

typedef __bf16 bf16x8 __attribute__((ext_vector_type(8)));
typedef float  floatx4 __attribute__((ext_vector_type(4)));

#define MFMA16(a, b, c) __builtin_amdgcn_mfma_f32_16x16x32_bf16((a), (b), (c), 0, 0, 0)

// Problem constants (B=4, S=4096, D=512, P=512)
static constexpr int BATCH = 4;
static constexpr int SEQ   = 4096;
static constexpr int MTOT  = BATCH * SEQ;  // 16384

// Async global->LDS DMA, 16B per lane (wave writes 1KB contiguous at ldst).
__device__ __forceinline__ void gload16(const void* gsrc, void* ldst)
{
    auto* g = reinterpret_cast<const __attribute__((address_space(1))) unsigned int*>(
        reinterpret_cast<unsigned long long>(gsrc));
    auto* l = reinterpret_cast<__attribute__((address_space(3))) unsigned int*>(
        reinterpret_cast<unsigned long long>(ldst));
    __builtin_amdgcn_global_load_lds(g, l, 16, 0, 0);
}

// ---------------------------------------------------------------------------
// Prep: x fp32 -> bf16 (row-major unchanged)
// ---------------------------------------------------------------------------
__global__ __launch_bounds__(256) void cvt_x(
    const float* __restrict__ x, __bf16* __restrict__ xb)
{
    const size_t i = ((size_t)blockIdx.x * 256 + threadIdx.x) * 8;
    const float4 a = *reinterpret_cast<const float4*>(x + i);
    const float4 c = *reinterpret_cast<const float4*>(x + i + 4);
    bf16x8 r;
    r[0] = (__bf16)a.x; r[1] = (__bf16)a.y; r[2] = (__bf16)a.z; r[3] = (__bf16)a.w;
    r[4] = (__bf16)c.x; r[5] = (__bf16)c.y; r[6] = (__bf16)c.z; r[7] = (__bf16)c.w;
    *reinterpret_cast<bf16x8*>(xb + i) = r;
}

// ---------------------------------------------------------------------------
// Prep: W [k][n] fp32 -> WT [n][k] bf16 (512x512), 64 blocks per matrix
// ---------------------------------------------------------------------------
__global__ __launch_bounds__(256) void transpose_w(
    const float* __restrict__ W, __bf16* __restrict__ WT)
{
    __shared__ __bf16 tile[64 * 68];
    const int t   = blockIdx.x;
    const int k0  = (t >> 3) * 64;
    const int n0  = (t & 7) * 64;
    const int tid = threadIdx.x;
#pragma unroll
    for (int it = 0; it < 4; ++it) {
        const int flat = it * 1024 + tid * 4;
        const int r = flat >> 6;   // k
        const int c = flat & 63;   // n
        const float4 v = *reinterpret_cast<const float4*>(
            W + (size_t)(k0 + r) * 512 + n0 + c);
        tile[r * 68 + c + 0] = (__bf16)v.x;
        tile[r * 68 + c + 1] = (__bf16)v.y;
        tile[r * 68 + c + 2] = (__bf16)v.z;
        tile[r * 68 + c + 3] = (__bf16)v.w;
    }
    __syncthreads();
#pragma unroll
    for (int it = 0; it < 2; ++it) {
        const int gid = it * 256 + tid;
        const int n  = gid >> 3;
        const int k8 = (gid & 7) * 8;
        bf16x8 r8;
#pragma unroll
        for (int j = 0; j < 8; ++j) r8[j] = tile[(k8 + j) * 68 + n];
        *reinterpret_cast<bf16x8*>(WT + (size_t)(n0 + n) * 512 + k0 + k8) = r8;
    }
}

// ---------------------------------------------------------------------------
// Fused QKV projection (all-bf16 inputs, gload_lds staging + XOR swizzle):
// Q = 0.125*(xb WqT^T + bq), K = xb WkT^T + bk, V -> vbT[b][p][t].
// ---------------------------------------------------------------------------
__global__ __launch_bounds__(256, 2) void qkv_gemm(
    const __bf16* __restrict__ xb,
    const __bf16* __restrict__ WqT, const float* __restrict__ bq,
    const __bf16* __restrict__ WkT, const float* __restrict__ bk,
    const __bf16* __restrict__ WvT, const float* __restrict__ bv,
    __bf16* __restrict__ qb, __bf16* __restrict__ kb, __bf16* __restrict__ vbT)
{
    __shared__ __attribute__((aligned(16))) __bf16 As[64 * 64];
    __shared__ __attribute__((aligned(16))) __bf16 Bq[64 * 64];
    __shared__ __attribute__((aligned(16))) __bf16 Bk[64 * 64];
    __shared__ __attribute__((aligned(16))) __bf16 Bv[64 * 64];
    __shared__ __bf16 Cs[64 * 80];

    const int tid  = threadIdx.x;
    const int w    = tid >> 6;
    const int lane = tid & 63;
    const int quad = lane >> 4;
    const int l15  = lane & 15;
    const int fid  = blockIdx.x;           // 0..2047
    const int n0   = (fid & 7) * 64;       // XCD-group = W column block
    const int m0   = (fid >> 3) * 64;

    const int srow0 = w * 8 + (lane >> 3);
    const int sgrp  = lane & 7;

    floatx4 aq[4], ak[4], av[4];
#pragma unroll
    for (int nt = 0; nt < 4; ++nt) {
        aq[nt] = floatx4{0.f, 0.f, 0.f, 0.f};
        ak[nt] = floatx4{0.f, 0.f, 0.f, 0.f};
        av[nt] = floatx4{0.f, 0.f, 0.f, 0.f};
    }

    for (int k0 = 0; k0 < 512; k0 += 64) {
#pragma unroll
        for (int i = 0; i < 2; ++i) {
            const int r  = i * 32 + srow0;
            const int cg = (sgrp ^ (r & 7)) << 3;     // inverse-swizzled source
            const int db = (i * 32 + w * 8) * 64;     // wave-uniform LDS base
            gload16(xb  + (size_t)(m0 + r) * 512 + k0 + cg, &As[db]);
            gload16(WqT + (size_t)(n0 + r) * 512 + k0 + cg, &Bq[db]);
            gload16(WkT + (size_t)(n0 + r) * 512 + k0 + cg, &Bk[db]);
            gload16(WvT + (size_t)(n0 + r) * 512 + k0 + cg, &Bv[db]);
        }
        __syncthreads();

#pragma unroll
        for (int kk = 0; kk < 2; ++kk) {
            const int arow = w * 16 + l15;
            const bf16x8 af = *reinterpret_cast<const bf16x8*>(
                &As[arow * 64 + (((kk * 4 + quad) ^ (arow & 7)) << 3)]);
#pragma unroll
            for (int nt = 0; nt < 4; ++nt) {
                const int brow = nt * 16 + l15;
                const int off  = brow * 64 + (((kk * 4 + quad) ^ (brow & 7)) << 3);
                aq[nt] = MFMA16(af, *reinterpret_cast<const bf16x8*>(&Bq[off]), aq[nt]);
                ak[nt] = MFMA16(af, *reinterpret_cast<const bf16x8*>(&Bk[off]), ak[nt]);
                av[nt] = MFMA16(af, *reinterpret_cast<const bf16x8*>(&Bv[off]), av[nt]);
            }
        }
        __syncthreads();
    }

    // Epilogue: Q,K row-major; V into Cs (transposed) then coalesced vbT write
#pragma unroll
    for (int nt = 0; nt < 4; ++nt) {
        const int col = n0 + nt * 16 + l15;
        const float bqv = bq[col], bkv = bk[col], bvv = bv[col];
#pragma unroll
        for (int r = 0; r < 4; ++r) {
            const int row = m0 + w * 16 + quad * 4 + r;
            qb[(size_t)row * 512 + col] = (__bf16)((aq[nt][r] + bqv) * 0.125f);
            kb[(size_t)row * 512 + col] = (__bf16)(ak[nt][r] + bkv);
            Cs[(nt * 16 + l15) * 80 + w * 16 + quad * 4 + r] = (__bf16)(av[nt][r] + bvv);
        }
    }
    __syncthreads();
    {
        const int bb = m0 >> 12;
        const int tb = m0 & 4095;
        __bf16* yb = vbT + (size_t)bb * 512 * 4096;
#pragma unroll
        for (int it = 0; it < 2; ++it) {
            const int flat = it * 2048 + tid * 8;
            const int pl = flat >> 6;
            const int c  = flat & 63;
            const bf16x8 vv = *reinterpret_cast<const bf16x8*>(&Cs[pl * 80 + c]);
            *reinterpret_cast<bf16x8*>(&yb[(size_t)(n0 + pl) * 4096 + tb + c]) = vv;
        }
    }
}

// ---------------------------------------------------------------------------
// Output GEMM: out[M x 512] = attended(bf16) WoT^T + bo (fp32 out).
// ---------------------------------------------------------------------------
__global__ __launch_bounds__(256, 2) void out_gemm(
    const __bf16* __restrict__ A, const __bf16* __restrict__ WT,
    const float* __restrict__ bias, float* __restrict__ Y)
{
    __shared__ __attribute__((aligned(16))) __bf16 As[64 * 64];
    __shared__ __attribute__((aligned(16))) __bf16 Bs[64 * 64];

    const int tid  = threadIdx.x;
    const int w    = tid >> 6;
    const int lane = tid & 63;
    const int quad = lane >> 4;
    const int l15  = lane & 15;
    const int fid  = blockIdx.x;
    const int n0   = (fid & 7) * 64;
    const int m0   = (fid >> 3) * 64;

    const int srow0 = w * 8 + (lane >> 3);
    const int sgrp  = lane & 7;

    floatx4 acc[4];
#pragma unroll
    for (int nt = 0; nt < 4; ++nt) acc[nt] = floatx4{0.f, 0.f, 0.f, 0.f};

    for (int k0 = 0; k0 < 512; k0 += 64) {
#pragma unroll
        for (int i = 0; i < 2; ++i) {
            const int r  = i * 32 + srow0;
            const int cg = (sgrp ^ (r & 7)) << 3;
            const int db = (i * 32 + w * 8) * 64;
            gload16(A  + (size_t)(m0 + r) * 512 + k0 + cg, &As[db]);
            gload16(WT + (size_t)(n0 + r) * 512 + k0 + cg, &Bs[db]);
        }
        __syncthreads();

#pragma unroll
        for (int kk = 0; kk < 2; ++kk) {
            const int arow = w * 16 + l15;
            const bf16x8 af = *reinterpret_cast<const bf16x8*>(
                &As[arow * 64 + (((kk * 4 + quad) ^ (arow & 7)) << 3)]);
#pragma unroll
            for (int nt = 0; nt < 4; ++nt) {
                const int brow = nt * 16 + l15;
                const bf16x8 bfv = *reinterpret_cast<const bf16x8*>(
                    &Bs[brow * 64 + (((kk * 4 + quad) ^ (brow & 7)) << 3)]);
                acc[nt] = MFMA16(af, bfv, acc[nt]);
            }
        }
        __syncthreads();
    }

#pragma unroll
    for (int nt = 0; nt < 4; ++nt) {
        const int col = n0 + nt * 16 + l15;
        const float bv = bias[col];
#pragma unroll
        for (int r = 0; r < 4; ++r) {
            const int row = m0 + w * 16 + quad * 4 + r;
            Y[(size_t)row * 512 + col] = acc[nt][r] + bv;
        }
    }
}

// ---------------------------------------------------------------------------
// Flash attention R9 = R6 schedule (QBLK=128, 8 waves, 256 blocks, plain
// wave-private-P PV, counted vmcnt) with KVBLK 32 -> 64: HALF the iterations
// (32 vs 64) => half the barrier/vmcnt/phase-ramp overhead, 2x independent
// work per phase for LDS-latency hiding. LDS 147KB (1 block/CU, 2 w/SIMD).
// Vt[512][64] XOR swizzle: source key-group (lane&7)^(lane>>3) on DMA,
// read group ((kk*4+quad)^(l15&7)) -> 2-way banked (free), same involution.
// ---------------------------------------------------------------------------
__global__ __launch_bounds__(512, 1) void flash_attn(
    const __bf16* __restrict__ q, const __bf16* __restrict__ k,
    const __bf16* __restrict__ vT, __bf16* __restrict__ pO,
    float* __restrict__ lP)
{
    __shared__ __attribute__((aligned(16))) __bf16 SH[75264]; // 147KB
    __bf16* Kt = SH;            // [64][520]  (66560B)
    __bf16* Vt = SH + 33280;    // [512][64]  (65536B), XOR-swizzled
    __bf16* Pl = SH + 66048;    // [128][72]  (18432B), wave-private rows

    const int tid  = threadIdx.x;
    const int w    = tid >> 6;      // 0..7 = row group
    const int lane = tid & 63;
    const int quad = lane >> 4;
    const int l15  = lane & 15;

    const int fid = blockIdx.x;     // 0..255
    const int g   = fid & 7;        // XCD group = (batch, half)
    const int hb  = g & 1;
    const int b   = g >> 1;
    const int q0  = (fid >> 3) * 128;
    const size_t boff = (size_t)b * SEQ * 512;

    // Q fragments (pre-scaled by 0.125): rows q0 + w*16 + l15, A-layout
    bf16x8 qf[16];
    {
        const __bf16* qrow = q + boff + (size_t)(q0 + w * 16 + l15) * 512;
#pragma unroll
        for (int kk = 0; kk < 16; ++kk)
            qf[kk] = *reinterpret_cast<const bf16x8*>(qrow + kk * 32 + quad * 8);
    }

    floatx4 o[32];
#pragma unroll
    for (int i = 0; i < 32; ++i) o[i] = floatx4{0.f, 0.f, 0.f, 0.f};
    float lsum[4] = {0.f, 0.f, 0.f, 0.f};

    const __bf16* kB  = k + boff;
    const __bf16* vTb = vT + boff;
    const int tstart = hb * 2048;
    const int tend   = tstart + 2048;

    const int vrow8 = lane >> 3;                        // 0..7 (p-row in 8-group)
    const int vkoff = (((lane & 7) ^ vrow8) << 3);      // pre-swizzled src key

    // K: wave w stages keys [w*8, w*8+8) (1KB rows). V: wave w stages
    // p-rows [(w*8+j)*8, +8) per DMA (8 rows x 128B = 1KB).
    auto issueK = [&](int t0) {
        const __bf16* kbase = kB + (size_t)(t0 + w * 8) * 512 + lane * 8;
#pragma unroll
        for (int j = 0; j < 8; ++j)
            gload16(kbase + (size_t)j * 512, &Kt[(w * 8 + j) * 520]);
    };
    auto issueV = [&](int t0) {
#pragma unroll
        for (int j = 0; j < 8; ++j) {
            const int p0 = (w * 8 + j) * 8;
            gload16(vTb + (size_t)(p0 + vrow8) * 4096 + t0 + vkoff, &Vt[p0 * 64]);
        }
    };

    issueK(tstart);
    issueV(tstart);

    for (int t0 = tstart; t0 < tend; t0 += 64) {
        const int tn = (t0 + 64 < tend) ? t0 + 64 : t0;   // clamp: re-load last

        // ---- phase 1: QK^T on Kt(t); V(t) still in flight (8 outstanding)
        asm volatile("s_waitcnt vmcnt(8)" ::: "memory");
        __builtin_amdgcn_s_barrier();

        floatx4 sa[4];
#pragma unroll
        for (int nt = 0; nt < 4; ++nt) sa[nt] = floatx4{0.f, 0.f, 0.f, 0.f};
        __builtin_amdgcn_s_setprio(1);
#pragma unroll
        for (int kk = 0; kk < 16; ++kk) {
#pragma unroll
            for (int nt = 0; nt < 4; ++nt) {
                const bf16x8 kf = *reinterpret_cast<const bf16x8*>(
                    &Kt[(nt * 16 + l15) * 520 + kk * 32 + quad * 8]);
                sa[nt] = MFMA16(qf[kk], kf, sa[nt]);
            }
        }
        __builtin_amdgcn_s_setprio(0);

        // P = exp(s), accumulate l, stash P (wave-private rows, 64 keys)
#pragma unroll
        for (int nt = 0; nt < 4; ++nt) {
#pragma unroll
            for (int r = 0; r < 4; ++r) {
                const float pv = __expf(sa[nt][r]);
                lsum[r] += pv;
                Pl[(w * 16 + quad * 4 + r) * 72 + nt * 16 + l15] = (__bf16)pv;
            }
        }

        __builtin_amdgcn_s_barrier();   // all waves done reading Kt(t)

        issueK(tn);                     // K(t+1) over Kt, flies under PV

        // ---- phase 2: PV on Vt(t); K(t+1) in flight (8 outstanding)
        asm volatile("s_waitcnt vmcnt(8)" ::: "memory");
        __builtin_amdgcn_s_barrier();

        const bf16x8 pf0 = *reinterpret_cast<const bf16x8*>(
            &Pl[(w * 16 + l15) * 72 + quad * 8]);
        const bf16x8 pf1 = *reinterpret_cast<const bf16x8*>(
            &Pl[(w * 16 + l15) * 72 + 32 + quad * 8]);
        const int sw0 = ((quad ^ (l15 & 7)) << 3);
        const int sw1 = (((4 + quad) ^ (l15 & 7)) << 3);
        __builtin_amdgcn_s_setprio(1);
#pragma unroll
        for (int pt = 0; pt < 32; ++pt) {
            const int row = (pt * 16 + l15) * 64;
            const bf16x8 vf0 = *reinterpret_cast<const bf16x8*>(&Vt[row + sw0]);
            const bf16x8 vf1 = *reinterpret_cast<const bf16x8*>(&Vt[row + sw1]);
            o[pt] = MFMA16(pf0, vf0, o[pt]);
            o[pt] = MFMA16(pf1, vf1, o[pt]);
        }
        __builtin_amdgcn_s_setprio(0);

        __builtin_amdgcn_s_barrier();   // all waves done reading Vt(t)

        issueV(tn);                     // V(t+1) over Vt, flies under next QK^T
    }
    asm volatile("s_waitcnt vmcnt(0)" ::: "memory");  // drain tail DMA

    // ---- final l (16-lane reduce) and partial writes
#pragma unroll
    for (int r = 0; r < 4; ++r) {
#pragma unroll
        for (int off = 1; off < 16; off <<= 1)
            lsum[r] += __shfl_xor(lsum[r], off);
    }
    const int rowbase = b * SEQ + q0 + w * 16 + quad * 4;
    if (l15 == 0) {
#pragma unroll
        for (int r = 0; r < 4; ++r)
            lP[(size_t)hb * MTOT + rowbase + r] = lsum[r];
    }
    __bf16* pOh = pO + (size_t)hb * MTOT * 512;
#pragma unroll
    for (int pt = 0; pt < 32; ++pt) {
#pragma unroll
        for (int r = 0; r < 4; ++r)
            pOh[(size_t)(rowbase + r) * 512 + pt * 16 + l15] = (__bf16)o[pt][r];
    }
}

// ---------------------------------------------------------------------------
// Merge the two key-half partials: att = (O0 + O1) / (l0 + l1)
// ---------------------------------------------------------------------------
__global__ __launch_bounds__(256) void merge_attn(
    const __bf16* __restrict__ pO, const float* __restrict__ lP,
    __bf16* __restrict__ att)
{
    const int gidx = blockIdx.x * 256 + threadIdx.x;  // 8-elem group
    const int row  = gidx >> 6;
    const int c8   = (gidx & 63) * 8;
    const float li = 1.0f / (lP[row] + lP[MTOT + row]);
    const bf16x8 a = *reinterpret_cast<const bf16x8*>(&pO[(size_t)row * 512 + c8]);
    const bf16x8 bvv = *reinterpret_cast<const bf16x8*>(
        &pO[((size_t)MTOT + row) * 512 + c8]);
    bf16x8 r8;
#pragma unroll
    for (int j = 0; j < 8; ++j)
        r8[j] = (__bf16)(((float)a[j] + (float)bvv[j]) * li);
    *reinterpret_cast<bf16x8*>(&att[(size_t)row * 512 + c8]) = r8;
}

// ---------------------------------------------------------------------------
extern "C" void kernel_launch(void* const* d_in, const int* in_sizes, int n_in,
                              void* d_out, int out_size, void* d_ws, size_t ws_size,
                              hipStream_t stream)
{
    (void)in_sizes; (void)n_in; (void)out_size; (void)ws_size;

    const float* x  = (const float*)d_in[0];
    const float* Wq = (const float*)d_in[1];
    const float* bq = (const float*)d_in[2];
    const float* Wk = (const float*)d_in[3];
    const float* bk = (const float*)d_in[4];
    const float* Wv = (const float*)d_in[5];
    const float* bv = (const float*)d_in[6];
    const float* Wo = (const float*)d_in[7];
    const float* bo = (const float*)d_in[8];
    float* out = (float*)d_out;

    // ws (48.1 MB): qb, kb, vbT (16 MB each) + lP. Scratch that is dead by
    // the time its region is overwritten:
    //   xb + WqT/WkT/WvT live in d_out (overwritten by pO during flash)
    //   WoT lives in kb (kb dead after flash)
    //   ab (attended) overlays qb (dead after flash)
    __bf16* qb  = (__bf16*)d_ws;
    __bf16* kb  = qb  + (size_t)MTOT * 512;
    __bf16* vbT = kb  + (size_t)MTOT * 512;
    float*  lP  = (float*)(vbT + (size_t)MTOT * 512);
    __bf16* pO  = (__bf16*)d_out;
    __bf16* ab  = qb;

    __bf16* xb  = (__bf16*)d_out;
    __bf16* WqT = xb  + (size_t)MTOT * 512;
    __bf16* WkT = WqT + 512 * 512;
    __bf16* WvT = WkT + 512 * 512;
    __bf16* WoT = kb;

    cvt_x<<<MTOT * 512 / 2048, 256, 0, stream>>>(x, xb);
    transpose_w<<<64, 256, 0, stream>>>(Wq, WqT);
    transpose_w<<<64, 256, 0, stream>>>(Wk, WkT);
    transpose_w<<<64, 256, 0, stream>>>(Wv, WvT);

    qkv_gemm<<<2048, 256, 0, stream>>>(xb, WqT, bq, WkT, bk, WvT, bv, qb, kb, vbT);

    flash_attn<<<256, 512, 0, stream>>>(qb, kb, vbT, pO, lP);

    transpose_w<<<64, 256, 0, stream>>>(Wo, WoT);
    merge_attn<<<MTOT * 64 / 256, 256, 0, stream>>>(pO, lP, ab);

    out_gemm<<<2048, 256, 0, stream>>>(ab, WoT, bo, out);
}

// Round 10
// 317.891 us; speedup vs baseline: 2.2663x; 2.2663x over previous
//
#include <hip/hip_runtime.h>
#include <hip/hip_bf16.h>

typedef __bf16 bf16x8 __attribute__((ext_vector_type(8)));
typedef float  floatx4 __attribute__((ext_vector_type(4)));

#define MFMA16(a, b, c) __builtin_amdgcn_mfma_f32_16x16x32_bf16((a), (b), (c), 0, 0, 0)

// Problem constants (B=4, S=4096, D=512, P=512)
static constexpr int BATCH = 4;
static constexpr int SEQ   = 4096;
static constexpr int MTOT  = BATCH * SEQ;  // 16384

// Async global->LDS DMA, 16B per lane (wave writes 1KB contiguous at ldst).
__device__ __forceinline__ void gload16(const void* gsrc, void* ldst)
{
    auto* g = reinterpret_cast<const __attribute__((address_space(1))) unsigned int*>(
        reinterpret_cast<unsigned long long>(gsrc));
    auto* l = reinterpret_cast<__attribute__((address_space(3))) unsigned int*>(
        reinterpret_cast<unsigned long long>(ldst));
    __builtin_amdgcn_global_load_lds(g, l, 16, 0, 0);
}

// ---------------------------------------------------------------------------
// Prep: x fp32 -> bf16 (row-major unchanged)
// ---------------------------------------------------------------------------
__global__ __launch_bounds__(256) void cvt_x(
    const float* __restrict__ x, __bf16* __restrict__ xb)
{
    const size_t i = ((size_t)blockIdx.x * 256 + threadIdx.x) * 8;
    const float4 a = *reinterpret_cast<const float4*>(x + i);
    const float4 c = *reinterpret_cast<const float4*>(x + i + 4);
    bf16x8 r;
    r[0] = (__bf16)a.x; r[1] = (__bf16)a.y; r[2] = (__bf16)a.z; r[3] = (__bf16)a.w;
    r[4] = (__bf16)c.x; r[5] = (__bf16)c.y; r[6] = (__bf16)c.z; r[7] = (__bf16)c.w;
    *reinterpret_cast<bf16x8*>(xb + i) = r;
}

// ---------------------------------------------------------------------------
// Prep: W [k][n] fp32 -> WT [n][k] bf16 (512x512), 64 blocks per matrix
// ---------------------------------------------------------------------------
__global__ __launch_bounds__(256) void transpose_w(
    const float* __restrict__ W, __bf16* __restrict__ WT)
{
    __shared__ __bf16 tile[64 * 68];
    const int t   = blockIdx.x;
    const int k0  = (t >> 3) * 64;
    const int n0  = (t & 7) * 64;
    const int tid = threadIdx.x;
#pragma unroll
    for (int it = 0; it < 4; ++it) {
        const int flat = it * 1024 + tid * 4;
        const int r = flat >> 6;   // k
        const int c = flat & 63;   // n
        const float4 v = *reinterpret_cast<const float4*>(
            W + (size_t)(k0 + r) * 512 + n0 + c);
        tile[r * 68 + c + 0] = (__bf16)v.x;
        tile[r * 68 + c + 1] = (__bf16)v.y;
        tile[r * 68 + c + 2] = (__bf16)v.z;
        tile[r * 68 + c + 3] = (__bf16)v.w;
    }
    __syncthreads();
#pragma unroll
    for (int it = 0; it < 2; ++it) {
        const int gid = it * 256 + tid;
        const int n  = gid >> 3;
        const int k8 = (gid & 7) * 8;
        bf16x8 r8;
#pragma unroll
        for (int j = 0; j < 8; ++j) r8[j] = tile[(k8 + j) * 68 + n];
        *reinterpret_cast<bf16x8*>(WT + (size_t)(n0 + n) * 512 + k0 + k8) = r8;
    }
}

// ---------------------------------------------------------------------------
// Fused QKV projection, BM=128 x BN=64 x BK=64 (m93-class tile).
// 4 waves; wave w owns rows w*32..+32, all 64 cols, 3 outputs.
// gload_lds staging + XOR swizzle (proven pattern). acc = 96 VGPR.
// Q = 0.125*(xb WqT^T + bq), K = xb WkT^T + bk, V -> vbT[b][p][t].
// ---------------------------------------------------------------------------
__global__ __launch_bounds__(256, 2) void qkv_gemm(
    const __bf16* __restrict__ xb,
    const __bf16* __restrict__ WqT, const float* __restrict__ bq,
    const __bf16* __restrict__ WkT, const float* __restrict__ bk,
    const __bf16* __restrict__ WvT, const float* __restrict__ bv,
    __bf16* __restrict__ qb, __bf16* __restrict__ kb, __bf16* __restrict__ vbT)
{
    __shared__ __attribute__((aligned(16))) __bf16 As[128 * 64];  // 16KB
    __shared__ __attribute__((aligned(16))) __bf16 Bq[64 * 64];   // 8KB
    __shared__ __attribute__((aligned(16))) __bf16 Bk[64 * 64];
    __shared__ __attribute__((aligned(16))) __bf16 Bv[64 * 64];
    __shared__ __attribute__((aligned(16))) __bf16 Cs[64 * 144];  // 18KB

    const int tid  = threadIdx.x;
    const int w    = tid >> 6;
    const int lane = tid & 63;
    const int quad = lane >> 4;
    const int l15  = lane & 15;
    const int fid  = blockIdx.x;           // 0..1023
    const int n0   = (fid & 7) * 64;       // XCD-group = W column block
    const int m0   = (fid >> 3) * 128;

    const int srow8 = lane >> 3;           // 0..7 (row within 8-row DMA)
    const int sgrp  = lane & 7;

    floatx4 aq[2][4], ak[2][4], av[2][4];
#pragma unroll
    for (int rf = 0; rf < 2; ++rf)
#pragma unroll
        for (int cf = 0; cf < 4; ++cf) {
            aq[rf][cf] = floatx4{0.f, 0.f, 0.f, 0.f};
            ak[rf][cf] = floatx4{0.f, 0.f, 0.f, 0.f};
            av[rf][cf] = floatx4{0.f, 0.f, 0.f, 0.f};
        }

    for (int k0 = 0; k0 < 512; k0 += 64) {
        // ---- stage A (128x64, 4 DMAs/wave) + 3x B (64x64, 2 DMAs/wave each)
#pragma unroll
        for (int i = 0; i < 4; ++i) {
            const int r  = w * 32 + i * 8 + srow8;
            const int cg = (sgrp ^ (r & 7)) << 3;
            gload16(xb + (size_t)(m0 + r) * 512 + k0 + cg,
                    &As[(w * 32 + i * 8) * 64]);
        }
#pragma unroll
        for (int i = 0; i < 2; ++i) {
            const int r  = w * 16 + i * 8 + srow8;
            const int cg = (sgrp ^ (r & 7)) << 3;
            const int db = (w * 16 + i * 8) * 64;
            gload16(WqT + (size_t)(n0 + r) * 512 + k0 + cg, &Bq[db]);
            gload16(WkT + (size_t)(n0 + r) * 512 + k0 + cg, &Bk[db]);
            gload16(WvT + (size_t)(n0 + r) * 512 + k0 + cg, &Bv[db]);
        }
        __syncthreads();   // drains vmcnt(0) -> all DMA landed

#pragma unroll
        for (int kk = 0; kk < 2; ++kk) {
            bf16x8 af[2];
#pragma unroll
            for (int rf = 0; rf < 2; ++rf) {
                const int arow = w * 32 + rf * 16 + l15;
                af[rf] = *reinterpret_cast<const bf16x8*>(
                    &As[arow * 64 + (((kk * 4 + quad) ^ (arow & 7)) << 3)]);
            }
#pragma unroll
            for (int cf = 0; cf < 4; ++cf) {
                const int brow = cf * 16 + l15;
                const int off  = brow * 64 + (((kk * 4 + quad) ^ (brow & 7)) << 3);
                const bf16x8 bfq = *reinterpret_cast<const bf16x8*>(&Bq[off]);
                const bf16x8 bfk = *reinterpret_cast<const bf16x8*>(&Bk[off]);
                const bf16x8 bfv = *reinterpret_cast<const bf16x8*>(&Bv[off]);
#pragma unroll
                for (int rf = 0; rf < 2; ++rf) {
                    aq[rf][cf] = MFMA16(af[rf], bfq, aq[rf][cf]);
                    ak[rf][cf] = MFMA16(af[rf], bfk, ak[rf][cf]);
                    av[rf][cf] = MFMA16(af[rf], bfv, av[rf][cf]);
                }
            }
        }
        __syncthreads();
    }

    // Epilogue: Q,K row-major; V into Cs (transposed [p][t], stride 144)
#pragma unroll
    for (int cf = 0; cf < 4; ++cf) {
        const int col = n0 + cf * 16 + l15;
        const float bqv = bq[col], bkv = bk[col], bvv = bv[col];
#pragma unroll
        for (int rf = 0; rf < 2; ++rf) {
#pragma unroll
            for (int r = 0; r < 4; ++r) {
                const int tl  = w * 32 + rf * 16 + quad * 4 + r;
                const int row = m0 + tl;
                qb[(size_t)row * 512 + col] = (__bf16)((aq[rf][cf][r] + bqv) * 0.125f);
                kb[(size_t)row * 512 + col] = (__bf16)(ak[rf][cf][r] + bkv);
                Cs[(cf * 16 + l15) * 144 + tl] = (__bf16)(av[rf][cf][r] + bvv);
            }
        }
    }
    __syncthreads();
    {
        const int bb = m0 >> 12;
        const int tb = m0 & 4095;
        __bf16* yb = vbT + (size_t)bb * 512 * 4096;
#pragma unroll
        for (int it = 0; it < 4; ++it) {
            const int flat = it * 2048 + tid * 8;
            const int pl = flat >> 7;      // p-local 0..63
            const int c  = flat & 127;     // token-local, multiple of 8
            const bf16x8 vv = *reinterpret_cast<const bf16x8*>(&Cs[pl * 144 + c]);
            *reinterpret_cast<bf16x8*>(&yb[(size_t)(n0 + pl) * 4096 + tb + c]) = vv;
        }
    }
}

// ---------------------------------------------------------------------------
// Output GEMM: 128x128x64 tile (m97 geometry). out = attended WoT^T + bo.
// 4 waves; wave w owns rows w*32..+32, all 128 cols. acc = 64 VGPR.
// ---------------------------------------------------------------------------
__global__ __launch_bounds__(256, 2) void out_gemm(
    const __bf16* __restrict__ A, const __bf16* __restrict__ WT,
    const float* __restrict__ bias, float* __restrict__ Y)
{
    __shared__ __attribute__((aligned(16))) __bf16 As[128 * 64];  // 16KB
    __shared__ __attribute__((aligned(16))) __bf16 Bs[128 * 64];  // 16KB

    const int tid  = threadIdx.x;
    const int w    = tid >> 6;
    const int lane = tid & 63;
    const int quad = lane >> 4;
    const int l15  = lane & 15;
    const int fid  = blockIdx.x;           // 0..511
    const int n0   = (fid & 3) * 128;
    const int m0   = (fid >> 2) * 128;

    const int srow8 = lane >> 3;
    const int sgrp  = lane & 7;

    floatx4 acc[2][8];
#pragma unroll
    for (int rf = 0; rf < 2; ++rf)
#pragma unroll
        for (int cf = 0; cf < 8; ++cf) acc[rf][cf] = floatx4{0.f, 0.f, 0.f, 0.f};

    for (int k0 = 0; k0 < 512; k0 += 64) {
#pragma unroll
        for (int i = 0; i < 4; ++i) {
            const int r  = w * 32 + i * 8 + srow8;
            const int cg = (sgrp ^ (r & 7)) << 3;
            gload16(A  + (size_t)(m0 + r) * 512 + k0 + cg,
                    &As[(w * 32 + i * 8) * 64]);
            gload16(WT + (size_t)(n0 + r) * 512 + k0 + cg,
                    &Bs[(w * 32 + i * 8) * 64]);
        }
        __syncthreads();

#pragma unroll
        for (int kk = 0; kk < 2; ++kk) {
            bf16x8 af[2];
#pragma unroll
            for (int rf = 0; rf < 2; ++rf) {
                const int arow = w * 32 + rf * 16 + l15;
                af[rf] = *reinterpret_cast<const bf16x8*>(
                    &As[arow * 64 + (((kk * 4 + quad) ^ (arow & 7)) << 3)]);
            }
#pragma unroll
            for (int cf = 0; cf < 8; ++cf) {
                const int brow = cf * 16 + l15;
                const bf16x8 bfv = *reinterpret_cast<const bf16x8*>(
                    &Bs[brow * 64 + (((kk * 4 + quad) ^ (brow & 7)) << 3)]);
#pragma unroll
                for (int rf = 0; rf < 2; ++rf)
                    acc[rf][cf] = MFMA16(af[rf], bfv, acc[rf][cf]);
            }
        }
        __syncthreads();
    }

#pragma unroll
    for (int cf = 0; cf < 8; ++cf) {
        const int col = n0 + cf * 16 + l15;
        const float bv = bias[col];
#pragma unroll
        for (int rf = 0; rf < 2; ++rf) {
#pragma unroll
            for (int r = 0; r < 4; ++r) {
                const int row = m0 + w * 32 + rf * 16 + quad * 4 + r;
                Y[(size_t)row * 512 + col] = acc[rf][cf][r] + bv;
            }
        }
    }
}

// ---------------------------------------------------------------------------
// Flash attention = R6's proven kernel VERBATIM (flash 180us; the 32-key
// tile is also the L2-friendliness sweet spot — R9's 64-key tile collapsed
// L2 hit rate, FETCH 33->430MB). QBLK=128, 8 waves, 256 blocks, 2-phase
// counted-vmcnt(4) pipeline, g=fid&7 XCD grouping.
// ---------------------------------------------------------------------------
__global__ __launch_bounds__(512, 2) void flash_attn(
    const __bf16* __restrict__ q, const __bf16* __restrict__ k,
    const __bf16* __restrict__ vT, __bf16* __restrict__ pO,
    float* __restrict__ lP)
{
    __shared__ __bf16 Kt[32 * 520];    // [key][p], padded stride 520
    __shared__ __bf16 Vt[512 * 32];    // [p][key], unpadded + XOR swizzle
    __shared__ __bf16 Pl[8 * 16 * 40]; // per-wave P: [w*16+row][key], stride 40

    const int tid  = threadIdx.x;
    const int w    = tid >> 6;      // 0..7 = row group
    const int lane = tid & 63;
    const int quad = lane >> 4;
    const int l15  = lane & 15;

    const int fid = blockIdx.x;     // 0..255
    const int g   = fid & 7;        // XCD group = (batch, half)
    const int hb  = g & 1;
    const int b   = g >> 1;
    const int q0  = (fid >> 3) * 128;
    const size_t boff = (size_t)b * SEQ * 512;

    // Q fragments (pre-scaled by 0.125): rows q0 + w*16 + l15, A-layout
    bf16x8 qf[16];
    {
        const __bf16* qrow = q + boff + (size_t)(q0 + w * 16 + l15) * 512;
#pragma unroll
        for (int kk = 0; kk < 16; ++kk)
            qf[kk] = *reinterpret_cast<const bf16x8*>(qrow + kk * 32 + quad * 8);
    }

    floatx4 o[32];
#pragma unroll
    for (int i = 0; i < 32; ++i) o[i] = floatx4{0.f, 0.f, 0.f, 0.f};
    float lsum[4] = {0.f, 0.f, 0.f, 0.f};

    const __bf16* kB  = k + boff;
    const __bf16* vTb = vT + boff;
    const int tstart = hb * 2048;
    const int tend   = tstart + 2048;

    const int vprow = lane >> 2;                                  // 0..15
    const int vkoff = (((lane & 3) ^ ((lane >> 3) & 3)) << 3);    // pre-swz src

    // ---- prologue: issue K(t0) then V(t0) (4 + 4 DMAs per wave)
    {
        const __bf16* kbase = kB + (size_t)(tstart + w * 4) * 512 + lane * 8;
#pragma unroll
        for (int j = 0; j < 4; ++j)
            gload16(kbase + (size_t)j * 512, &Kt[(w * 4 + j) * 520]);
#pragma unroll
        for (int j = 0; j < 4; ++j) {
            const int p0 = (w * 4 + j) * 16;
            gload16(vTb + (size_t)(p0 + vprow) * 4096 + tstart + vkoff, &Vt[p0 * 32]);
        }
    }

    for (int t0 = tstart; t0 < tend; t0 += 32) {
        const int tn = (t0 + 32 < tend) ? t0 + 32 : t0;   // clamp: re-load last

        // ---- phase 1: QK^T on Kt(t); V(t) still in flight (4 outstanding)
        asm volatile("s_waitcnt vmcnt(4)" ::: "memory");
        __builtin_amdgcn_s_barrier();

        floatx4 sa0 = floatx4{0.f, 0.f, 0.f, 0.f};
        floatx4 sa1 = floatx4{0.f, 0.f, 0.f, 0.f};
        __builtin_amdgcn_s_setprio(1);
#pragma unroll
        for (int kk = 0; kk < 16; ++kk) {
            const bf16x8 kf0 = *reinterpret_cast<const bf16x8*>(
                &Kt[l15 * 520 + kk * 32 + quad * 8]);
            const bf16x8 kf1 = *reinterpret_cast<const bf16x8*>(
                &Kt[(16 + l15) * 520 + kk * 32 + quad * 8]);
            sa0 = MFMA16(qf[kk], kf0, sa0);
            sa1 = MFMA16(qf[kk], kf1, sa1);
        }
        __builtin_amdgcn_s_setprio(0);

        // P = exp(s), accumulate l, stash P (wave-private rows -> no barrier)
#pragma unroll
        for (int r = 0; r < 4; ++r) {
            const float p0 = __expf(sa0[r]);
            const float p1 = __expf(sa1[r]);
            lsum[r] += p0 + p1;
            Pl[(w * 16 + quad * 4 + r) * 40 + l15]      = (__bf16)p0;
            Pl[(w * 16 + quad * 4 + r) * 40 + 16 + l15] = (__bf16)p1;
        }

        __builtin_amdgcn_s_barrier();   // all waves done reading Kt(t)

        {   // issue K(t+1) over Kt
            const __bf16* kbase = kB + (size_t)(tn + w * 4) * 512 + lane * 8;
#pragma unroll
            for (int j = 0; j < 4; ++j)
                gload16(kbase + (size_t)j * 512, &Kt[(w * 4 + j) * 520]);
        }

        // ---- phase 2: PV on Vt(t); K(t+1) in flight (4 outstanding)
        asm volatile("s_waitcnt vmcnt(4)" ::: "memory");
        __builtin_amdgcn_s_barrier();

        const bf16x8 pf = *reinterpret_cast<const bf16x8*>(
            &Pl[(w * 16 + l15) * 40 + quad * 8]);
        const int vsw = ((quad ^ ((l15 >> 1) & 3)) << 3);
        __builtin_amdgcn_s_setprio(1);
#pragma unroll
        for (int pt = 0; pt < 32; ++pt) {
            const bf16x8 vf = *reinterpret_cast<const bf16x8*>(
                &Vt[(pt * 16 + l15) * 32 + vsw]);
            o[pt] = MFMA16(pf, vf, o[pt]);
        }
        __builtin_amdgcn_s_setprio(0);

        __builtin_amdgcn_s_barrier();   // all waves done reading Vt(t)

#pragma unroll
        for (int j = 0; j < 4; ++j) {   // issue V(t+1) over Vt
            const int p0 = (w * 4 + j) * 16;
            gload16(vTb + (size_t)(p0 + vprow) * 4096 + tn + vkoff, &Vt[p0 * 32]);
        }
    }
    asm volatile("s_waitcnt vmcnt(0)" ::: "memory");  // drain tail DMA

    // ---- final l (16-lane reduce) and partial writes
#pragma unroll
    for (int r = 0; r < 4; ++r) {
#pragma unroll
        for (int off = 1; off < 16; off <<= 1)
            lsum[r] += __shfl_xor(lsum[r], off);
    }
    const int rowbase = b * SEQ + q0 + w * 16 + quad * 4;
    if (l15 == 0) {
#pragma unroll
        for (int r = 0; r < 4; ++r)
            lP[(size_t)hb * MTOT + rowbase + r] = lsum[r];
    }
    __bf16* pOh = pO + (size_t)hb * MTOT * 512;
#pragma unroll
    for (int pt = 0; pt < 32; ++pt) {
#pragma unroll
        for (int r = 0; r < 4; ++r)
            pOh[(size_t)(rowbase + r) * 512 + pt * 16 + l15] = (__bf16)o[pt][r];
    }
}

// ---------------------------------------------------------------------------
// Merge the two key-half partials: att = (O0 + O1) / (l0 + l1)
// ---------------------------------------------------------------------------
__global__ __launch_bounds__(256) void merge_attn(
    const __bf16* __restrict__ pO, const float* __restrict__ lP,
    __bf16* __restrict__ att)
{
    const int gidx = blockIdx.x * 256 + threadIdx.x;  // 8-elem group
    const int row  = gidx >> 6;
    const int c8   = (gidx & 63) * 8;
    const float li = 1.0f / (lP[row] + lP[MTOT + row]);
    const bf16x8 a = *reinterpret_cast<const bf16x8*>(&pO[(size_t)row * 512 + c8]);
    const bf16x8 bvv = *reinterpret_cast<const bf16x8*>(
        &pO[((size_t)MTOT + row) * 512 + c8]);
    bf16x8 r8;
#pragma unroll
    for (int j = 0; j < 8; ++j)
        r8[j] = (__bf16)(((float)a[j] + (float)bvv[j]) * li);
    *reinterpret_cast<bf16x8*>(&att[(size_t)row * 512 + c8]) = r8;
}

// ---------------------------------------------------------------------------
extern "C" void kernel_launch(void* const* d_in, const int* in_sizes, int n_in,
                              void* d_out, int out_size, void* d_ws, size_t ws_size,
                              hipStream_t stream)
{
    (void)in_sizes; (void)n_in; (void)out_size; (void)ws_size;

    const float* x  = (const float*)d_in[0];
    const float* Wq = (const float*)d_in[1];
    const float* bq = (const float*)d_in[2];
    const float* Wk = (const float*)d_in[3];
    const float* bk = (const float*)d_in[4];
    const float* Wv = (const float*)d_in[5];
    const float* bv = (const float*)d_in[6];
    const float* Wo = (const float*)d_in[7];
    const float* bo = (const float*)d_in[8];
    float* out = (float*)d_out;

    // ws (48.1 MB): qb, kb, vbT (16 MB each) + lP. Scratch that is dead by
    // the time its region is overwritten:
    //   xb + WqT/WkT/WvT live in d_out (overwritten by pO during flash)
    //   WoT lives in kb (kb dead after flash)
    //   ab (attended) overlays qb (dead after flash)
    __bf16* qb  = (__bf16*)d_ws;
    __bf16* kb  = qb  + (size_t)MTOT * 512;
    __bf16* vbT = kb  + (size_t)MTOT * 512;
    float*  lP  = (float*)(vbT + (size_t)MTOT * 512);
    __bf16* pO  = (__bf16*)d_out;
    __bf16* ab  = qb;

    __bf16* xb  = (__bf16*)d_out;
    __bf16* WqT = xb  + (size_t)MTOT * 512;
    __bf16* WkT = WqT + 512 * 512;
    __bf16* WvT = WkT + 512 * 512;
    __bf16* WoT = kb;

    cvt_x<<<MTOT * 512 / 2048, 256, 0, stream>>>(x, xb);
    transpose_w<<<64, 256, 0, stream>>>(Wq, WqT);
    transpose_w<<<64, 256, 0, stream>>>(Wk, WkT);
    transpose_w<<<64, 256, 0, stream>>>(Wv, WvT);

    qkv_gemm<<<1024, 256, 0, stream>>>(xb, WqT, bq, WkT, bk, WvT, bv, qb, kb, vbT);

    flash_attn<<<256, 512, 0, stream>>>(qb, kb, vbT, pO, lP);

    transpose_w<<<64, 256, 0, stream>>>(Wo, WoT);
    merge_attn<<<MTOT * 64 / 256, 256, 0, stream>>>(pO, lP, ab);

    out_gemm<<<512, 256, 0, stream>>>(ab, WoT, bo, out);
}

// Round 11
// 308.189 us; speedup vs baseline: 2.3376x; 1.0315x over previous
//
#include <hip/hip_runtime.h>
#include <hip/hip_bf16.h>

typedef __bf16 bf16x8 __attribute__((ext_vector_type(8)));
typedef float  floatx4 __attribute__((ext_vector_type(4)));

#define MFMA16(a, b, c) __builtin_amdgcn_mfma_f32_16x16x32_bf16((a), (b), (c), 0, 0, 0)

// Problem constants (B=4, S=4096, D=512, P=512)
static constexpr int BATCH = 4;
static constexpr int SEQ   = 4096;
static constexpr int MTOT  = BATCH * SEQ;  // 16384

// Async global->LDS DMA, 16B per lane (wave writes 1KB contiguous at ldst).
__device__ __forceinline__ void gload16(const void* gsrc, void* ldst)
{
    auto* g = reinterpret_cast<const __attribute__((address_space(1))) unsigned int*>(
        reinterpret_cast<unsigned long long>(gsrc));
    auto* l = reinterpret_cast<__attribute__((address_space(3))) unsigned int*>(
        reinterpret_cast<unsigned long long>(ldst));
    __builtin_amdgcn_global_load_lds(g, l, 16, 0, 0);
}

// ---------------------------------------------------------------------------
// Fused prep: blocks [0,4096) convert x fp32->bf16; blocks [4096,4288)
// transpose Wq/Wk/Wv ([k][n] fp32 -> [n][k] bf16, 64 tiles each).
// ---------------------------------------------------------------------------
__global__ __launch_bounds__(256) void prep(
    const float* __restrict__ x, __bf16* __restrict__ xb,
    const float* __restrict__ Wq, const float* __restrict__ Wk,
    const float* __restrict__ Wv,
    __bf16* __restrict__ WqT, __bf16* __restrict__ WkT, __bf16* __restrict__ WvT)
{
    __shared__ __bf16 tile[64 * 68];
    const int bid = blockIdx.x;
    const int tid = threadIdx.x;

    if (bid < 4096) {   // x conversion
        const size_t i = ((size_t)bid * 256 + tid) * 8;
        const float4 a = *reinterpret_cast<const float4*>(x + i);
        const float4 c = *reinterpret_cast<const float4*>(x + i + 4);
        bf16x8 r;
        r[0] = (__bf16)a.x; r[1] = (__bf16)a.y; r[2] = (__bf16)a.z; r[3] = (__bf16)a.w;
        r[4] = (__bf16)c.x; r[5] = (__bf16)c.y; r[6] = (__bf16)c.z; r[7] = (__bf16)c.w;
        *reinterpret_cast<bf16x8*>(xb + i) = r;
        return;
    }

    const int t  = bid - 4096;          // 0..191
    const int m  = t >> 6;              // matrix 0..2
    const int tl = t & 63;
    const float* W = (m == 0) ? Wq : (m == 1) ? Wk : Wv;
    __bf16*     WT = (m == 0) ? WqT : (m == 1) ? WkT : WvT;
    const int k0 = (tl >> 3) * 64;
    const int n0 = (tl & 7) * 64;

#pragma unroll
    for (int it = 0; it < 4; ++it) {
        const int flat = it * 1024 + tid * 4;
        const int r = flat >> 6;   // k
        const int c = flat & 63;   // n
        const float4 v = *reinterpret_cast<const float4*>(
            W + (size_t)(k0 + r) * 512 + n0 + c);
        tile[r * 68 + c + 0] = (__bf16)v.x;
        tile[r * 68 + c + 1] = (__bf16)v.y;
        tile[r * 68 + c + 2] = (__bf16)v.z;
        tile[r * 68 + c + 3] = (__bf16)v.w;
    }
    __syncthreads();
#pragma unroll
    for (int it = 0; it < 2; ++it) {
        const int gid = it * 256 + tid;
        const int n  = gid >> 3;
        const int k8 = (gid & 7) * 8;
        bf16x8 r8;
#pragma unroll
        for (int j = 0; j < 8; ++j) r8[j] = tile[(k8 + j) * 68 + n];
        *reinterpret_cast<bf16x8*>(WT + (size_t)(n0 + n) * 512 + k0 + k8) = r8;
    }
}

// ---------------------------------------------------------------------------
// Fused QKV projection, BM=128 x BN=64 x BK=64 (R10-proven).
// Q = 0.125*(xb WqT^T + bq), K = xb WkT^T + bk, V -> vbT[b][p][t].
// ---------------------------------------------------------------------------
__global__ __launch_bounds__(256, 2) void qkv_gemm(
    const __bf16* __restrict__ xb,
    const __bf16* __restrict__ WqT, const float* __restrict__ bq,
    const __bf16* __restrict__ WkT, const float* __restrict__ bk,
    const __bf16* __restrict__ WvT, const float* __restrict__ bv,
    __bf16* __restrict__ qb, __bf16* __restrict__ kb, __bf16* __restrict__ vbT)
{
    __shared__ __attribute__((aligned(16))) __bf16 As[128 * 64];  // 16KB
    __shared__ __attribute__((aligned(16))) __bf16 Bq[64 * 64];   // 8KB
    __shared__ __attribute__((aligned(16))) __bf16 Bk[64 * 64];
    __shared__ __attribute__((aligned(16))) __bf16 Bv[64 * 64];
    __shared__ __attribute__((aligned(16))) __bf16 Cs[64 * 144];  // 18KB

    const int tid  = threadIdx.x;
    const int w    = tid >> 6;
    const int lane = tid & 63;
    const int quad = lane >> 4;
    const int l15  = lane & 15;
    const int fid  = blockIdx.x;           // 0..1023
    const int n0   = (fid & 7) * 64;       // XCD-group = W column block
    const int m0   = (fid >> 3) * 128;

    const int srow8 = lane >> 3;
    const int sgrp  = lane & 7;

    floatx4 aq[2][4], ak[2][4], av[2][4];
#pragma unroll
    for (int rf = 0; rf < 2; ++rf)
#pragma unroll
        for (int cf = 0; cf < 4; ++cf) {
            aq[rf][cf] = floatx4{0.f, 0.f, 0.f, 0.f};
            ak[rf][cf] = floatx4{0.f, 0.f, 0.f, 0.f};
            av[rf][cf] = floatx4{0.f, 0.f, 0.f, 0.f};
        }

    for (int k0 = 0; k0 < 512; k0 += 64) {
#pragma unroll
        for (int i = 0; i < 4; ++i) {
            const int r  = w * 32 + i * 8 + srow8;
            const int cg = (sgrp ^ (r & 7)) << 3;
            gload16(xb + (size_t)(m0 + r) * 512 + k0 + cg,
                    &As[(w * 32 + i * 8) * 64]);
        }
#pragma unroll
        for (int i = 0; i < 2; ++i) {
            const int r  = w * 16 + i * 8 + srow8;
            const int cg = (sgrp ^ (r & 7)) << 3;
            const int db = (w * 16 + i * 8) * 64;
            gload16(WqT + (size_t)(n0 + r) * 512 + k0 + cg, &Bq[db]);
            gload16(WkT + (size_t)(n0 + r) * 512 + k0 + cg, &Bk[db]);
            gload16(WvT + (size_t)(n0 + r) * 512 + k0 + cg, &Bv[db]);
        }
        __syncthreads();

#pragma unroll
        for (int kk = 0; kk < 2; ++kk) {
            bf16x8 af[2];
#pragma unroll
            for (int rf = 0; rf < 2; ++rf) {
                const int arow = w * 32 + rf * 16 + l15;
                af[rf] = *reinterpret_cast<const bf16x8*>(
                    &As[arow * 64 + (((kk * 4 + quad) ^ (arow & 7)) << 3)]);
            }
#pragma unroll
            for (int cf = 0; cf < 4; ++cf) {
                const int brow = cf * 16 + l15;
                const int off  = brow * 64 + (((kk * 4 + quad) ^ (brow & 7)) << 3);
                const bf16x8 bfq = *reinterpret_cast<const bf16x8*>(&Bq[off]);
                const bf16x8 bfk = *reinterpret_cast<const bf16x8*>(&Bk[off]);
                const bf16x8 bfv = *reinterpret_cast<const bf16x8*>(&Bv[off]);
#pragma unroll
                for (int rf = 0; rf < 2; ++rf) {
                    aq[rf][cf] = MFMA16(af[rf], bfq, aq[rf][cf]);
                    ak[rf][cf] = MFMA16(af[rf], bfk, ak[rf][cf]);
                    av[rf][cf] = MFMA16(af[rf], bfv, av[rf][cf]);
                }
            }
        }
        __syncthreads();
    }

    // Epilogue: Q,K row-major; V into Cs (transposed [p][t], stride 144)
#pragma unroll
    for (int cf = 0; cf < 4; ++cf) {
        const int col = n0 + cf * 16 + l15;
        const float bqv = bq[col], bkv = bk[col], bvv = bv[col];
#pragma unroll
        for (int rf = 0; rf < 2; ++rf) {
#pragma unroll
            for (int r = 0; r < 4; ++r) {
                const int tl  = w * 32 + rf * 16 + quad * 4 + r;
                const int row = m0 + tl;
                qb[(size_t)row * 512 + col] = (__bf16)((aq[rf][cf][r] + bqv) * 0.125f);
                kb[(size_t)row * 512 + col] = (__bf16)(ak[rf][cf][r] + bkv);
                Cs[(cf * 16 + l15) * 144 + tl] = (__bf16)(av[rf][cf][r] + bvv);
            }
        }
    }
    __syncthreads();
    {
        const int bb = m0 >> 12;
        const int tb = m0 & 4095;
        __bf16* yb = vbT + (size_t)bb * 512 * 4096;
#pragma unroll
        for (int it = 0; it < 4; ++it) {
            const int flat = it * 2048 + tid * 8;
            const int pl = flat >> 7;      // p-local 0..63
            const int c  = flat & 127;     // token-local, multiple of 8
            const bf16x8 vv = *reinterpret_cast<const bf16x8*>(&Cs[pl * 144 + c]);
            *reinterpret_cast<bf16x8*>(&yb[(size_t)(n0 + pl) * 4096 + tb + c]) = vv;
        }
    }
}

// ---------------------------------------------------------------------------
// Output GEMM: 128x128x64 tile (R10-proven). out = attended WoT^T + bo.
// ---------------------------------------------------------------------------
__global__ __launch_bounds__(256, 2) void out_gemm(
    const __bf16* __restrict__ A, const __bf16* __restrict__ WT,
    const float* __restrict__ bias, float* __restrict__ Y)
{
    __shared__ __attribute__((aligned(16))) __bf16 As[128 * 64];  // 16KB
    __shared__ __attribute__((aligned(16))) __bf16 Bs[128 * 64];  // 16KB

    const int tid  = threadIdx.x;
    const int w    = tid >> 6;
    const int lane = tid & 63;
    const int quad = lane >> 4;
    const int l15  = lane & 15;
    const int fid  = blockIdx.x;           // 0..511
    const int n0   = (fid & 3) * 128;
    const int m0   = (fid >> 2) * 128;

    const int srow8 = lane >> 3;
    const int sgrp  = lane & 7;

    floatx4 acc[2][8];
#pragma unroll
    for (int rf = 0; rf < 2; ++rf)
#pragma unroll
        for (int cf = 0; cf < 8; ++cf) acc[rf][cf] = floatx4{0.f, 0.f, 0.f, 0.f};

    for (int k0 = 0; k0 < 512; k0 += 64) {
#pragma unroll
        for (int i = 0; i < 4; ++i) {
            const int r  = w * 32 + i * 8 + srow8;
            const int cg = (sgrp ^ (r & 7)) << 3;
            gload16(A  + (size_t)(m0 + r) * 512 + k0 + cg,
                    &As[(w * 32 + i * 8) * 64]);
            gload16(WT + (size_t)(n0 + r) * 512 + k0 + cg,
                    &Bs[(w * 32 + i * 8) * 64]);
        }
        __syncthreads();

#pragma unroll
        for (int kk = 0; kk < 2; ++kk) {
            bf16x8 af[2];
#pragma unroll
            for (int rf = 0; rf < 2; ++rf) {
                const int arow = w * 32 + rf * 16 + l15;
                af[rf] = *reinterpret_cast<const bf16x8*>(
                    &As[arow * 64 + (((kk * 4 + quad) ^ (arow & 7)) << 3)]);
            }
#pragma unroll
            for (int cf = 0; cf < 8; ++cf) {
                const int brow = cf * 16 + l15;
                const bf16x8 bfv = *reinterpret_cast<const bf16x8*>(
                    &Bs[brow * 64 + (((kk * 4 + quad) ^ (brow & 7)) << 3)]);
#pragma unroll
                for (int rf = 0; rf < 2; ++rf)
                    acc[rf][cf] = MFMA16(af[rf], bfv, acc[rf][cf]);
            }
        }
        __syncthreads();
    }

#pragma unroll
    for (int cf = 0; cf < 8; ++cf) {
        const int col = n0 + cf * 16 + l15;
        const float bv = bias[col];
#pragma unroll
        for (int rf = 0; rf < 2; ++rf) {
#pragma unroll
            for (int r = 0; r < 4; ++r) {
                const int row = m0 + w * 32 + rf * 16 + quad * 4 + r;
                Y[(size_t)row * 512 + col] = acc[rf][cf][r] + bv;
            }
        }
    }
}

// ---------------------------------------------------------------------------
// Flash attention = R7's verified kernel (177.2-177.7us vs R6's 180.4-181):
// QBLK=128, 8 waves, 256 blocks, 2-phase counted-vmcnt(4), transposed PV
// (wave owns p-slice w*64..+64 for ALL 128 rows; 4 V-frag + 8 P reads) and
// coalesced Ot-through-LDS epilogue. g=fid&7 XCD grouping.
// ---------------------------------------------------------------------------
__global__ __launch_bounds__(512, 2) void flash_attn(
    const __bf16* __restrict__ q, const __bf16* __restrict__ k,
    const __bf16* __restrict__ vT, __bf16* __restrict__ pO,
    float* __restrict__ lP)
{
    __shared__ __attribute__((aligned(16))) __bf16 SH[38144]; // 74.5KB
    __bf16* Kt = SH;            // [32][520]  (16640)
    __bf16* Vt = SH + 16640;    // [512][32]  (16384), XOR-swizzled
    __bf16* Pl = SH + 33024;    // [128][40]  (5120)

    const int tid  = threadIdx.x;
    const int w    = tid >> 6;      // 0..7 = row group (QKT) / p-slice (PV)
    const int lane = tid & 63;
    const int quad = lane >> 4;
    const int l15  = lane & 15;

    const int fid = blockIdx.x;     // 0..255
    const int g   = fid & 7;        // XCD group = (batch, half)
    const int hb  = g & 1;
    const int b   = g >> 1;
    const int q0  = (fid >> 3) * 128;
    const size_t boff = (size_t)b * SEQ * 512;

    // Q fragments (pre-scaled by 0.125): rows q0 + w*16 + l15, A-layout
    bf16x8 qf[16];
    {
        const __bf16* qrow = q + boff + (size_t)(q0 + w * 16 + l15) * 512;
#pragma unroll
        for (int kk = 0; kk < 16; ++kk)
            qf[kk] = *reinterpret_cast<const bf16x8*>(qrow + kk * 32 + quad * 8);
    }

    // o[pb*8+rb]: O^T[p = (w*4+pb)*16 + quad*4 + r][qrow = rb*16 + l15]
    floatx4 o[32];
#pragma unroll
    for (int i = 0; i < 32; ++i) o[i] = floatx4{0.f, 0.f, 0.f, 0.f};
    float lsum[4] = {0.f, 0.f, 0.f, 0.f};

    const __bf16* kB  = k + boff;
    const __bf16* vTb = vT + boff;
    const int tstart = hb * 2048;
    const int tend   = tstart + 2048;

    const int vprow = lane >> 2;                                  // 0..15
    const int vkoff = (((lane & 3) ^ ((lane >> 3) & 3)) << 3);    // pre-swz src
    const int vsw   = ((quad ^ ((l15 >> 1) & 3)) << 3);           // read swz

    // ---- prologue: issue K(t0) then V(t0) (4 + 4 DMAs per wave)
    {
        const __bf16* kbase = kB + (size_t)(tstart + w * 4) * 512 + lane * 8;
#pragma unroll
        for (int j = 0; j < 4; ++j)
            gload16(kbase + (size_t)j * 512, &Kt[(w * 4 + j) * 520]);
#pragma unroll
        for (int j = 0; j < 4; ++j) {
            const int p0 = (w * 4 + j) * 16;
            gload16(vTb + (size_t)(p0 + vprow) * 4096 + tstart + vkoff, &Vt[p0 * 32]);
        }
    }

    for (int t0 = tstart; t0 < tend; t0 += 32) {
        const int tn = (t0 + 32 < tend) ? t0 + 32 : t0;   // clamp: re-load last

        // ---- phase 1: QK^T on Kt(t); V(t) still in flight (4 outstanding)
        asm volatile("s_waitcnt vmcnt(4)" ::: "memory");
        __builtin_amdgcn_s_barrier();

        floatx4 sa0 = floatx4{0.f, 0.f, 0.f, 0.f};
        floatx4 sa1 = floatx4{0.f, 0.f, 0.f, 0.f};
        __builtin_amdgcn_s_setprio(1);
#pragma unroll
        for (int kk = 0; kk < 16; ++kk) {
            const bf16x8 kf0 = *reinterpret_cast<const bf16x8*>(
                &Kt[l15 * 520 + kk * 32 + quad * 8]);
            const bf16x8 kf1 = *reinterpret_cast<const bf16x8*>(
                &Kt[(16 + l15) * 520 + kk * 32 + quad * 8]);
            sa0 = MFMA16(qf[kk], kf0, sa0);
            sa1 = MFMA16(qf[kk], kf1, sa1);
        }
        __builtin_amdgcn_s_setprio(0);

        // P = exp(s), accumulate l, stash P rows (read by ALL waves in PV)
#pragma unroll
        for (int r = 0; r < 4; ++r) {
            const float p0 = __expf(sa0[r]);
            const float p1 = __expf(sa1[r]);
            lsum[r] += p0 + p1;
            Pl[(w * 16 + quad * 4 + r) * 40 + l15]      = (__bf16)p0;
            Pl[(w * 16 + quad * 4 + r) * 40 + 16 + l15] = (__bf16)p1;
        }

        asm volatile("s_waitcnt lgkmcnt(0)" ::: "memory");  // P visible
        __builtin_amdgcn_s_barrier();   // all waves done reading Kt(t)

        {   // issue K(t+1) over Kt
            const __bf16* kbase = kB + (size_t)(tn + w * 4) * 512 + lane * 8;
#pragma unroll
            for (int j = 0; j < 4; ++j)
                gload16(kbase + (size_t)j * 512, &Kt[(w * 4 + j) * 520]);
        }

        // ---- phase 2: PV on Vt(t) + Pl; K(t+1) in flight (4 outstanding)
        asm volatile("s_waitcnt vmcnt(4)" ::: "memory");
        __builtin_amdgcn_s_barrier();

        bf16x8 vfr[4];
#pragma unroll
        for (int pb = 0; pb < 4; ++pb)
            vfr[pb] = *reinterpret_cast<const bf16x8*>(
                &Vt[((w * 4 + pb) * 16 + l15) * 32 + vsw]);

        __builtin_amdgcn_s_setprio(1);
#pragma unroll
        for (int rb = 0; rb < 8; ++rb) {
            const bf16x8 pf = *reinterpret_cast<const bf16x8*>(
                &Pl[(rb * 16 + l15) * 40 + quad * 8]);
#pragma unroll
            for (int pb = 0; pb < 4; ++pb)
                o[pb * 8 + rb] = MFMA16(vfr[pb], pf, o[pb * 8 + rb]);
        }
        __builtin_amdgcn_s_setprio(0);

        __builtin_amdgcn_s_barrier();   // all waves done reading Vt(t)/Pl(t)

#pragma unroll
        for (int j = 0; j < 4; ++j) {   // issue V(t+1) over Vt
            const int p0 = (w * 4 + j) * 16;
            gload16(vTb + (size_t)(p0 + vprow) * 4096 + tn + vkoff, &Vt[p0 * 32]);
        }
    }
    asm volatile("s_waitcnt vmcnt(0)" ::: "memory");  // drain own tail DMA

    // ---- final l (16-lane reduce over keys' lanes) and l write
#pragma unroll
    for (int r = 0; r < 4; ++r) {
#pragma unroll
        for (int off = 1; off < 16; off <<= 1)
            lsum[r] += __shfl_xor(lsum[r], off);
    }
    const int lrowbase = b * SEQ + q0 + w * 16 + quad * 4;
    if (l15 == 0) {
#pragma unroll
        for (int r = 0; r < 4; ++r)
            lP[(size_t)hb * MTOT + lrowbase + r] = lsum[r];
    }

    // ---- O epilogue: transpose via LDS (reuse SH), 2 halves of 64 rows
    __bf16* Ot = SH;                      // [64][520]
    __bf16* pOh = pO + (size_t)hb * MTOT * 512;
    const int prowbase = b * SEQ + q0;
#pragma unroll
    for (int hh = 0; hh < 2; ++hh) {
        __builtin_amdgcn_s_barrier();     // SH free (loop reads / prev half)
#pragma unroll
        for (int rb2 = 0; rb2 < 4; ++rb2) {
            const int rb = hh * 4 + rb2;
#pragma unroll
            for (int pb = 0; pb < 4; ++pb) {
#pragma unroll
                for (int r = 0; r < 4; ++r)
                    Ot[(rb2 * 16 + l15) * 520 + (w * 4 + pb) * 16 + quad * 4 + r] =
                        (__bf16)o[pb * 8 + rb][r];
            }
        }
        asm volatile("s_waitcnt lgkmcnt(0)" ::: "memory");
        __builtin_amdgcn_s_barrier();
#pragma unroll
        for (int it = 0; it < 8; ++it) {
            const int id  = it * 512 + tid;
            const int row = id >> 6;
            const int c8  = (id & 63) * 8;
            *reinterpret_cast<bf16x8*>(
                pOh + (size_t)(prowbase + hh * 64 + row) * 512 + c8) =
                *reinterpret_cast<const bf16x8*>(&Ot[row * 520 + c8]);
        }
    }
}

// ---------------------------------------------------------------------------
// Fused post-flash: blocks [0,64) transpose Wo -> WoT (into kb, dead after
// flash); blocks [64,4160) merge the two key-half partials:
// att = (O0 + O1) / (l0 + l1).
// ---------------------------------------------------------------------------
__global__ __launch_bounds__(256) void merge_wo(
    const __bf16* __restrict__ pO, const float* __restrict__ lP,
    __bf16* __restrict__ att,
    const float* __restrict__ Wo, __bf16* __restrict__ WoT)
{
    __shared__ __bf16 tile[64 * 68];
    const int bid = blockIdx.x;
    const int tid = threadIdx.x;

    if (bid < 64) {     // Wo transpose
        const int k0 = (bid >> 3) * 64;
        const int n0 = (bid & 7) * 64;
#pragma unroll
        for (int it = 0; it < 4; ++it) {
            const int flat = it * 1024 + tid * 4;
            const int r = flat >> 6;
            const int c = flat & 63;
            const float4 v = *reinterpret_cast<const float4*>(
                Wo + (size_t)(k0 + r) * 512 + n0 + c);
            tile[r * 68 + c + 0] = (__bf16)v.x;
            tile[r * 68 + c + 1] = (__bf16)v.y;
            tile[r * 68 + c + 2] = (__bf16)v.z;
            tile[r * 68 + c + 3] = (__bf16)v.w;
        }
        __syncthreads();
#pragma unroll
        for (int it = 0; it < 2; ++it) {
            const int gid = it * 256 + tid;
            const int n  = gid >> 3;
            const int k8 = (gid & 7) * 8;
            bf16x8 r8;
#pragma unroll
            for (int j = 0; j < 8; ++j) r8[j] = tile[(k8 + j) * 68 + n];
            *reinterpret_cast<bf16x8*>(WoT + (size_t)(n0 + n) * 512 + k0 + k8) = r8;
        }
        return;
    }

    const int gidx = (bid - 64) * 256 + tid;  // 8-elem group
    const int row  = gidx >> 6;
    const int c8   = (gidx & 63) * 8;
    const float li = 1.0f / (lP[row] + lP[MTOT + row]);
    const bf16x8 a = *reinterpret_cast<const bf16x8*>(&pO[(size_t)row * 512 + c8]);
    const bf16x8 bvv = *reinterpret_cast<const bf16x8*>(
        &pO[((size_t)MTOT + row) * 512 + c8]);
    bf16x8 r8;
#pragma unroll
    for (int j = 0; j < 8; ++j)
        r8[j] = (__bf16)(((float)a[j] + (float)bvv[j]) * li);
    *reinterpret_cast<bf16x8*>(&att[(size_t)row * 512 + c8]) = r8;
}

// ---------------------------------------------------------------------------
extern "C" void kernel_launch(void* const* d_in, const int* in_sizes, int n_in,
                              void* d_out, int out_size, void* d_ws, size_t ws_size,
                              hipStream_t stream)
{
    (void)in_sizes; (void)n_in; (void)out_size; (void)ws_size;

    const float* x  = (const float*)d_in[0];
    const float* Wq = (const float*)d_in[1];
    const float* bq = (const float*)d_in[2];
    const float* Wk = (const float*)d_in[3];
    const float* bk = (const float*)d_in[4];
    const float* Wv = (const float*)d_in[5];
    const float* bv = (const float*)d_in[6];
    const float* Wo = (const float*)d_in[7];
    const float* bo = (const float*)d_in[8];
    float* out = (float*)d_out;

    // ws (48.1 MB): qb, kb, vbT (16 MB each) + lP. Scratch that is dead by
    // the time its region is overwritten:
    //   xb + WqT/WkT/WvT live in d_out (overwritten by pO during flash)
    //   WoT lives in kb (kb dead after flash)
    //   ab (attended) overlays qb (dead after flash)
    __bf16* qb  = (__bf16*)d_ws;
    __bf16* kb  = qb  + (size_t)MTOT * 512;
    __bf16* vbT = kb  + (size_t)MTOT * 512;
    float*  lP  = (float*)(vbT + (size_t)MTOT * 512);
    __bf16* pO  = (__bf16*)d_out;
    __bf16* ab  = qb;

    __bf16* xb  = (__bf16*)d_out;
    __bf16* WqT = xb  + (size_t)MTOT * 512;
    __bf16* WkT = WqT + 512 * 512;
    __bf16* WvT = WkT + 512 * 512;
    __bf16* WoT = kb;

    prep<<<4288, 256, 0, stream>>>(x, xb, Wq, Wk, Wv, WqT, WkT, WvT);

    qkv_gemm<<<1024, 256, 0, stream>>>(xb, WqT, bq, WkT, bk, WvT, bv, qb, kb, vbT);

    flash_attn<<<256, 512, 0, stream>>>(qb, kb, vbT, pO, lP);

    merge_wo<<<4160, 256, 0, stream>>>(pO, lP, ab, Wo, WoT);

    out_gemm<<<512, 256, 0, stream>>>(ab, WoT, bo, out);
}

// Round 12
// 301.140 us; speedup vs baseline: 2.3924x; 1.0234x over previous
//
#include <hip/hip_runtime.h>
#include <hip/hip_bf16.h>

typedef __bf16 bf16x8 __attribute__((ext_vector_type(8)));
typedef float  floatx4 __attribute__((ext_vector_type(4)));

#define MFMA16(a, b, c) __builtin_amdgcn_mfma_f32_16x16x32_bf16((a), (b), (c), 0, 0, 0)

// Problem constants (B=4, S=4096, D=512, P=512)
static constexpr int BATCH = 4;
static constexpr int SEQ   = 4096;
static constexpr int MTOT  = BATCH * SEQ;  // 16384

// Async global->LDS DMA, 16B per lane (wave writes 1KB contiguous at ldst).
__device__ __forceinline__ void gload16(const void* gsrc, void* ldst)
{
    auto* g = reinterpret_cast<const __attribute__((address_space(1))) unsigned int*>(
        reinterpret_cast<unsigned long long>(gsrc));
    auto* l = reinterpret_cast<__attribute__((address_space(3))) unsigned int*>(
        reinterpret_cast<unsigned long long>(ldst));
    __builtin_amdgcn_global_load_lds(g, l, 16, 0, 0);
}

// ---------------------------------------------------------------------------
// Fused prep: blocks [0,4096) convert x fp32->bf16; blocks [4096,4288)
// transpose Wq/Wk/Wv ([k][n] fp32 -> [n][k] bf16, 64 tiles each).
// ---------------------------------------------------------------------------
__global__ __launch_bounds__(256) void prep(
    const float* __restrict__ x, __bf16* __restrict__ xb,
    const float* __restrict__ Wq, const float* __restrict__ Wk,
    const float* __restrict__ Wv,
    __bf16* __restrict__ WqT, __bf16* __restrict__ WkT, __bf16* __restrict__ WvT)
{
    __shared__ __bf16 tile[64 * 68];
    const int bid = blockIdx.x;
    const int tid = threadIdx.x;

    if (bid < 4096) {   // x conversion
        const size_t i = ((size_t)bid * 256 + tid) * 8;
        const float4 a = *reinterpret_cast<const float4*>(x + i);
        const float4 c = *reinterpret_cast<const float4*>(x + i + 4);
        bf16x8 r;
        r[0] = (__bf16)a.x; r[1] = (__bf16)a.y; r[2] = (__bf16)a.z; r[3] = (__bf16)a.w;
        r[4] = (__bf16)c.x; r[5] = (__bf16)c.y; r[6] = (__bf16)c.z; r[7] = (__bf16)c.w;
        *reinterpret_cast<bf16x8*>(xb + i) = r;
        return;
    }

    const int t  = bid - 4096;          // 0..191
    const int m  = t >> 6;              // matrix 0..2
    const int tl = t & 63;
    const float* W = (m == 0) ? Wq : (m == 1) ? Wk : Wv;
    __bf16*     WT = (m == 0) ? WqT : (m == 1) ? WkT : WvT;
    const int k0 = (tl >> 3) * 64;
    const int n0 = (tl & 7) * 64;

#pragma unroll
    for (int it = 0; it < 4; ++it) {
        const int flat = it * 1024 + tid * 4;
        const int r = flat >> 6;   // k
        const int c = flat & 63;   // n
        const float4 v = *reinterpret_cast<const float4*>(
            W + (size_t)(k0 + r) * 512 + n0 + c);
        tile[r * 68 + c + 0] = (__bf16)v.x;
        tile[r * 68 + c + 1] = (__bf16)v.y;
        tile[r * 68 + c + 2] = (__bf16)v.z;
        tile[r * 68 + c + 3] = (__bf16)v.w;
    }
    __syncthreads();
#pragma unroll
    for (int it = 0; it < 2; ++it) {
        const int gid = it * 256 + tid;
        const int n  = gid >> 3;
        const int k8 = (gid & 7) * 8;
        bf16x8 r8;
#pragma unroll
        for (int j = 0; j < 8; ++j) r8[j] = tile[(k8 + j) * 68 + n];
        *reinterpret_cast<bf16x8*>(WT + (size_t)(n0 + n) * 512 + k0 + k8) = r8;
    }
}

// ---------------------------------------------------------------------------
// Fused QKV projection, BM=128 x BN=64 x BK=64 (R10-proven compute).
// XCD grouping is m-CHUNKED (R12): each XCD owns a contiguous 2048-row
// slice of A (2MB, L2-fit) and iterates all 8 W-column blocks for it.
// W (1.5MB total) fits any L2 — A locality is what matters (A was being
// re-fetched by all 8 XCDs = 128MB of L3 traffic with the old n-grouping).
// Q = 0.125*(xb WqT^T + bq), K = xb WkT^T + bk, V -> vbT[b][p][t].
// ---------------------------------------------------------------------------
__global__ __launch_bounds__(256, 2) void qkv_gemm(
    const __bf16* __restrict__ xb,
    const __bf16* __restrict__ WqT, const float* __restrict__ bq,
    const __bf16* __restrict__ WkT, const float* __restrict__ bk,
    const __bf16* __restrict__ WvT, const float* __restrict__ bv,
    __bf16* __restrict__ qb, __bf16* __restrict__ kb, __bf16* __restrict__ vbT)
{
    __shared__ __attribute__((aligned(16))) __bf16 As[128 * 64];  // 16KB
    __shared__ __attribute__((aligned(16))) __bf16 Bq[64 * 64];   // 8KB
    __shared__ __attribute__((aligned(16))) __bf16 Bk[64 * 64];
    __shared__ __attribute__((aligned(16))) __bf16 Bv[64 * 64];
    __shared__ __attribute__((aligned(16))) __bf16 Cs[64 * 144];  // 18KB

    const int tid  = threadIdx.x;
    const int w    = tid >> 6;
    const int lane = tid & 63;
    const int quad = lane >> 4;
    const int l15  = lane & 15;
    const int fid  = blockIdx.x;           // 0..1023
    const int xcd  = fid & 7;              // XCD (round-robin dispatch)
    const int loc  = fid >> 3;             // 0..127
    const int m0   = (xcd * 16 + (loc >> 3)) * 128;  // m-chunk per XCD
    const int n0   = (loc & 7) * 64;

    const int srow8 = lane >> 3;
    const int sgrp  = lane & 7;

    floatx4 aq[2][4], ak[2][4], av[2][4];
#pragma unroll
    for (int rf = 0; rf < 2; ++rf)
#pragma unroll
        for (int cf = 0; cf < 4; ++cf) {
            aq[rf][cf] = floatx4{0.f, 0.f, 0.f, 0.f};
            ak[rf][cf] = floatx4{0.f, 0.f, 0.f, 0.f};
            av[rf][cf] = floatx4{0.f, 0.f, 0.f, 0.f};
        }

    for (int k0 = 0; k0 < 512; k0 += 64) {
#pragma unroll
        for (int i = 0; i < 4; ++i) {
            const int r  = w * 32 + i * 8 + srow8;
            const int cg = (sgrp ^ (r & 7)) << 3;
            gload16(xb + (size_t)(m0 + r) * 512 + k0 + cg,
                    &As[(w * 32 + i * 8) * 64]);
        }
#pragma unroll
        for (int i = 0; i < 2; ++i) {
            const int r  = w * 16 + i * 8 + srow8;
            const int cg = (sgrp ^ (r & 7)) << 3;
            const int db = (w * 16 + i * 8) * 64;
            gload16(WqT + (size_t)(n0 + r) * 512 + k0 + cg, &Bq[db]);
            gload16(WkT + (size_t)(n0 + r) * 512 + k0 + cg, &Bk[db]);
            gload16(WvT + (size_t)(n0 + r) * 512 + k0 + cg, &Bv[db]);
        }
        __syncthreads();

#pragma unroll
        for (int kk = 0; kk < 2; ++kk) {
            bf16x8 af[2];
#pragma unroll
            for (int rf = 0; rf < 2; ++rf) {
                const int arow = w * 32 + rf * 16 + l15;
                af[rf] = *reinterpret_cast<const bf16x8*>(
                    &As[arow * 64 + (((kk * 4 + quad) ^ (arow & 7)) << 3)]);
            }
#pragma unroll
            for (int cf = 0; cf < 4; ++cf) {
                const int brow = cf * 16 + l15;
                const int off  = brow * 64 + (((kk * 4 + quad) ^ (brow & 7)) << 3);
                const bf16x8 bfq = *reinterpret_cast<const bf16x8*>(&Bq[off]);
                const bf16x8 bfk = *reinterpret_cast<const bf16x8*>(&Bk[off]);
                const bf16x8 bfv = *reinterpret_cast<const bf16x8*>(&Bv[off]);
#pragma unroll
                for (int rf = 0; rf < 2; ++rf) {
                    aq[rf][cf] = MFMA16(af[rf], bfq, aq[rf][cf]);
                    ak[rf][cf] = MFMA16(af[rf], bfk, ak[rf][cf]);
                    av[rf][cf] = MFMA16(af[rf], bfv, av[rf][cf]);
                }
            }
        }
        __syncthreads();
    }

    // Epilogue: Q,K row-major; V into Cs (transposed [p][t], stride 144)
#pragma unroll
    for (int cf = 0; cf < 4; ++cf) {
        const int col = n0 + cf * 16 + l15;
        const float bqv = bq[col], bkv = bk[col], bvv = bv[col];
#pragma unroll
        for (int rf = 0; rf < 2; ++rf) {
#pragma unroll
            for (int r = 0; r < 4; ++r) {
                const int tl  = w * 32 + rf * 16 + quad * 4 + r;
                const int row = m0 + tl;
                qb[(size_t)row * 512 + col] = (__bf16)((aq[rf][cf][r] + bqv) * 0.125f);
                kb[(size_t)row * 512 + col] = (__bf16)(ak[rf][cf][r] + bkv);
                Cs[(cf * 16 + l15) * 144 + tl] = (__bf16)(av[rf][cf][r] + bvv);
            }
        }
    }
    __syncthreads();
    {
        const int bb = m0 >> 12;
        const int tb = m0 & 4095;
        __bf16* yb = vbT + (size_t)bb * 512 * 4096;
#pragma unroll
        for (int it = 0; it < 4; ++it) {
            const int flat = it * 2048 + tid * 8;
            const int pl = flat >> 7;      // p-local 0..63
            const int c  = flat & 127;     // token-local, multiple of 8
            const bf16x8 vv = *reinterpret_cast<const bf16x8*>(&Cs[pl * 144 + c]);
            *reinterpret_cast<bf16x8*>(&yb[(size_t)(n0 + pl) * 4096 + tb + c]) = vv;
        }
    }
}

// ---------------------------------------------------------------------------
// Output GEMM: 128x128x64 tile (R10-proven compute), m-chunked XCD grouping
// (R12): each XCD owns 2048 rows of A (2MB, L2-fit) across all 4 n-blocks.
// out = attended WoT^T + bo.
// ---------------------------------------------------------------------------
__global__ __launch_bounds__(256, 2) void out_gemm(
    const __bf16* __restrict__ A, const __bf16* __restrict__ WT,
    const float* __restrict__ bias, float* __restrict__ Y)
{
    __shared__ __attribute__((aligned(16))) __bf16 As[128 * 64];  // 16KB
    __shared__ __attribute__((aligned(16))) __bf16 Bs[128 * 64];  // 16KB

    const int tid  = threadIdx.x;
    const int w    = tid >> 6;
    const int lane = tid & 63;
    const int quad = lane >> 4;
    const int l15  = lane & 15;
    const int fid  = blockIdx.x;           // 0..511
    const int xcd  = fid & 7;
    const int loc  = fid >> 3;             // 0..63
    const int m0   = (xcd * 16 + (loc >> 2)) * 128;
    const int n0   = (loc & 3) * 128;

    const int srow8 = lane >> 3;
    const int sgrp  = lane & 7;

    floatx4 acc[2][8];
#pragma unroll
    for (int rf = 0; rf < 2; ++rf)
#pragma unroll
        for (int cf = 0; cf < 8; ++cf) acc[rf][cf] = floatx4{0.f, 0.f, 0.f, 0.f};

    for (int k0 = 0; k0 < 512; k0 += 64) {
#pragma unroll
        for (int i = 0; i < 4; ++i) {
            const int r  = w * 32 + i * 8 + srow8;
            const int cg = (sgrp ^ (r & 7)) << 3;
            gload16(A  + (size_t)(m0 + r) * 512 + k0 + cg,
                    &As[(w * 32 + i * 8) * 64]);
            gload16(WT + (size_t)(n0 + r) * 512 + k0 + cg,
                    &Bs[(w * 32 + i * 8) * 64]);
        }
        __syncthreads();

#pragma unroll
        for (int kk = 0; kk < 2; ++kk) {
            bf16x8 af[2];
#pragma unroll
            for (int rf = 0; rf < 2; ++rf) {
                const int arow = w * 32 + rf * 16 + l15;
                af[rf] = *reinterpret_cast<const bf16x8*>(
                    &As[arow * 64 + (((kk * 4 + quad) ^ (arow & 7)) << 3)]);
            }
#pragma unroll
            for (int cf = 0; cf < 8; ++cf) {
                const int brow = cf * 16 + l15;
                const bf16x8 bfv = *reinterpret_cast<const bf16x8*>(
                    &Bs[brow * 64 + (((kk * 4 + quad) ^ (brow & 7)) << 3)]);
#pragma unroll
                for (int rf = 0; rf < 2; ++rf)
                    acc[rf][cf] = MFMA16(af[rf], bfv, acc[rf][cf]);
            }
        }
        __syncthreads();
    }

#pragma unroll
    for (int cf = 0; cf < 8; ++cf) {
        const int col = n0 + cf * 16 + l15;
        const float bv = bias[col];
#pragma unroll
        for (int rf = 0; rf < 2; ++rf) {
#pragma unroll
            for (int r = 0; r < 4; ++r) {
                const int row = m0 + w * 32 + rf * 16 + quad * 4 + r;
                Y[(size_t)row * 512 + col] = acc[rf][cf][r] + bv;
            }
        }
    }
}

// ---------------------------------------------------------------------------
// Flash attention = R7/R11's verified kernel (175.2-175.6us):
// QBLK=128, 8 waves, 256 blocks, 2-phase counted-vmcnt(4), transposed PV
// (wave owns p-slice w*64..+64 for ALL 128 rows; 4 V-frag + 8 P reads) and
// coalesced Ot-through-LDS epilogue. g=fid&7 XCD grouping.
// ---------------------------------------------------------------------------
__global__ __launch_bounds__(512, 2) void flash_attn(
    const __bf16* __restrict__ q, const __bf16* __restrict__ k,
    const __bf16* __restrict__ vT, __bf16* __restrict__ pO,
    float* __restrict__ lP)
{
    __shared__ __attribute__((aligned(16))) __bf16 SH[38144]; // 74.5KB
    __bf16* Kt = SH;            // [32][520]  (16640)
    __bf16* Vt = SH + 16640;    // [512][32]  (16384), XOR-swizzled
    __bf16* Pl = SH + 33024;    // [128][40]  (5120)

    const int tid  = threadIdx.x;
    const int w    = tid >> 6;      // 0..7 = row group (QKT) / p-slice (PV)
    const int lane = tid & 63;
    const int quad = lane >> 4;
    const int l15  = lane & 15;

    const int fid = blockIdx.x;     // 0..255
    const int g   = fid & 7;        // XCD group = (batch, half)
    const int hb  = g & 1;
    const int b   = g >> 1;
    const int q0  = (fid >> 3) * 128;
    const size_t boff = (size_t)b * SEQ * 512;

    // Q fragments (pre-scaled by 0.125): rows q0 + w*16 + l15, A-layout
    bf16x8 qf[16];
    {
        const __bf16* qrow = q + boff + (size_t)(q0 + w * 16 + l15) * 512;
#pragma unroll
        for (int kk = 0; kk < 16; ++kk)
            qf[kk] = *reinterpret_cast<const bf16x8*>(qrow + kk * 32 + quad * 8);
    }

    // o[pb*8+rb]: O^T[p = (w*4+pb)*16 + quad*4 + r][qrow = rb*16 + l15]
    floatx4 o[32];
#pragma unroll
    for (int i = 0; i < 32; ++i) o[i] = floatx4{0.f, 0.f, 0.f, 0.f};
    float lsum[4] = {0.f, 0.f, 0.f, 0.f};

    const __bf16* kB  = k + boff;
    const __bf16* vTb = vT + boff;
    const int tstart = hb * 2048;
    const int tend   = tstart + 2048;

    const int vprow = lane >> 2;                                  // 0..15
    const int vkoff = (((lane & 3) ^ ((lane >> 3) & 3)) << 3);    // pre-swz src
    const int vsw   = ((quad ^ ((l15 >> 1) & 3)) << 3);           // read swz

    // ---- prologue: issue K(t0) then V(t0) (4 + 4 DMAs per wave)
    {
        const __bf16* kbase = kB + (size_t)(tstart + w * 4) * 512 + lane * 8;
#pragma unroll
        for (int j = 0; j < 4; ++j)
            gload16(kbase + (size_t)j * 512, &Kt[(w * 4 + j) * 520]);
#pragma unroll
        for (int j = 0; j < 4; ++j) {
            const int p0 = (w * 4 + j) * 16;
            gload16(vTb + (size_t)(p0 + vprow) * 4096 + tstart + vkoff, &Vt[p0 * 32]);
        }
    }

    for (int t0 = tstart; t0 < tend; t0 += 32) {
        const int tn = (t0 + 32 < tend) ? t0 + 32 : t0;   // clamp: re-load last

        // ---- phase 1: QK^T on Kt(t); V(t) still in flight (4 outstanding)
        asm volatile("s_waitcnt vmcnt(4)" ::: "memory");
        __builtin_amdgcn_s_barrier();

        floatx4 sa0 = floatx4{0.f, 0.f, 0.f, 0.f};
        floatx4 sa1 = floatx4{0.f, 0.f, 0.f, 0.f};
        __builtin_amdgcn_s_setprio(1);
#pragma unroll
        for (int kk = 0; kk < 16; ++kk) {
            const bf16x8 kf0 = *reinterpret_cast<const bf16x8*>(
                &Kt[l15 * 520 + kk * 32 + quad * 8]);
            const bf16x8 kf1 = *reinterpret_cast<const bf16x8*>(
                &Kt[(16 + l15) * 520 + kk * 32 + quad * 8]);
            sa0 = MFMA16(qf[kk], kf0, sa0);
            sa1 = MFMA16(qf[kk], kf1, sa1);
        }
        __builtin_amdgcn_s_setprio(0);

        // P = exp(s), accumulate l, stash P rows (read by ALL waves in PV)
#pragma unroll
        for (int r = 0; r < 4; ++r) {
            const float p0 = __expf(sa0[r]);
            const float p1 = __expf(sa1[r]);
            lsum[r] += p0 + p1;
            Pl[(w * 16 + quad * 4 + r) * 40 + l15]      = (__bf16)p0;
            Pl[(w * 16 + quad * 4 + r) * 40 + 16 + l15] = (__bf16)p1;
        }

        asm volatile("s_waitcnt lgkmcnt(0)" ::: "memory");  // P visible
        __builtin_amdgcn_s_barrier();   // all waves done reading Kt(t)

        {   // issue K(t+1) over Kt
            const __bf16* kbase = kB + (size_t)(tn + w * 4) * 512 + lane * 8;
#pragma unroll
            for (int j = 0; j < 4; ++j)
                gload16(kbase + (size_t)j * 512, &Kt[(w * 4 + j) * 520]);
        }

        // ---- phase 2: PV on Vt(t) + Pl; K(t+1) in flight (4 outstanding)
        asm volatile("s_waitcnt vmcnt(4)" ::: "memory");
        __builtin_amdgcn_s_barrier();

        bf16x8 vfr[4];
#pragma unroll
        for (int pb = 0; pb < 4; ++pb)
            vfr[pb] = *reinterpret_cast<const bf16x8*>(
                &Vt[((w * 4 + pb) * 16 + l15) * 32 + vsw]);

        __builtin_amdgcn_s_setprio(1);
#pragma unroll
        for (int rb = 0; rb < 8; ++rb) {
            const bf16x8 pf = *reinterpret_cast<const bf16x8*>(
                &Pl[(rb * 16 + l15) * 40 + quad * 8]);
#pragma unroll
            for (int pb = 0; pb < 4; ++pb)
                o[pb * 8 + rb] = MFMA16(vfr[pb], pf, o[pb * 8 + rb]);
        }
        __builtin_amdgcn_s_setprio(0);

        __builtin_amdgcn_s_barrier();   // all waves done reading Vt(t)/Pl(t)

#pragma unroll
        for (int j = 0; j < 4; ++j) {   // issue V(t+1) over Vt
            const int p0 = (w * 4 + j) * 16;
            gload16(vTb + (size_t)(p0 + vprow) * 4096 + tn + vkoff, &Vt[p0 * 32]);
        }
    }
    asm volatile("s_waitcnt vmcnt(0)" ::: "memory");  // drain own tail DMA

    // ---- final l (16-lane reduce over keys' lanes) and l write
#pragma unroll
    for (int r = 0; r < 4; ++r) {
#pragma unroll
        for (int off = 1; off < 16; off <<= 1)
            lsum[r] += __shfl_xor(lsum[r], off);
    }
    const int lrowbase = b * SEQ + q0 + w * 16 + quad * 4;
    if (l15 == 0) {
#pragma unroll
        for (int r = 0; r < 4; ++r)
            lP[(size_t)hb * MTOT + lrowbase + r] = lsum[r];
    }

    // ---- O epilogue: transpose via LDS (reuse SH), 2 halves of 64 rows
    __bf16* Ot = SH;                      // [64][520]
    __bf16* pOh = pO + (size_t)hb * MTOT * 512;
    const int prowbase = b * SEQ + q0;
#pragma unroll
    for (int hh = 0; hh < 2; ++hh) {
        __builtin_amdgcn_s_barrier();     // SH free (loop reads / prev half)
#pragma unroll
        for (int rb2 = 0; rb2 < 4; ++rb2) {
            const int rb = hh * 4 + rb2;
#pragma unroll
            for (int pb = 0; pb < 4; ++pb) {
#pragma unroll
                for (int r = 0; r < 4; ++r)
                    Ot[(rb2 * 16 + l15) * 520 + (w * 4 + pb) * 16 + quad * 4 + r] =
                        (__bf16)o[pb * 8 + rb][r];
            }
        }
        asm volatile("s_waitcnt lgkmcnt(0)" ::: "memory");
        __builtin_amdgcn_s_barrier();
#pragma unroll
        for (int it = 0; it < 8; ++it) {
            const int id  = it * 512 + tid;
            const int row = id >> 6;
            const int c8  = (id & 63) * 8;
            *reinterpret_cast<bf16x8*>(
                pOh + (size_t)(prowbase + hh * 64 + row) * 512 + c8) =
                *reinterpret_cast<const bf16x8*>(&Ot[row * 520 + c8]);
        }
    }
}

// ---------------------------------------------------------------------------
// Fused post-flash: blocks [0,64) transpose Wo -> WoT (into kb, dead after
// flash); blocks [64,4160) merge the two key-half partials:
// att = (O0 + O1) / (l0 + l1).
// ---------------------------------------------------------------------------
__global__ __launch_bounds__(256) void merge_wo(
    const __bf16* __restrict__ pO, const float* __restrict__ lP,
    __bf16* __restrict__ att,
    const float* __restrict__ Wo, __bf16* __restrict__ WoT)
{
    __shared__ __bf16 tile[64 * 68];
    const int bid = blockIdx.x;
    const int tid = threadIdx.x;

    if (bid < 64) {     // Wo transpose
        const int k0 = (bid >> 3) * 64;
        const int n0 = (bid & 7) * 64;
#pragma unroll
        for (int it = 0; it < 4; ++it) {
            const int flat = it * 1024 + tid * 4;
            const int r = flat >> 6;
            const int c = flat & 63;
            const float4 v = *reinterpret_cast<const float4*>(
                Wo + (size_t)(k0 + r) * 512 + n0 + c);
            tile[r * 68 + c + 0] = (__bf16)v.x;
            tile[r * 68 + c + 1] = (__bf16)v.y;
            tile[r * 68 + c + 2] = (__bf16)v.z;
            tile[r * 68 + c + 3] = (__bf16)v.w;
        }
        __syncthreads();
#pragma unroll
        for (int it = 0; it < 2; ++it) {
            const int gid = it * 256 + tid;
            const int n  = gid >> 3;
            const int k8 = (gid & 7) * 8;
            bf16x8 r8;
#pragma unroll
            for (int j = 0; j < 8; ++j) r8[j] = tile[(k8 + j) * 68 + n];
            *reinterpret_cast<bf16x8*>(WoT + (size_t)(n0 + n) * 512 + k0 + k8) = r8;
        }
        return;
    }

    const int gidx = (bid - 64) * 256 + tid;  // 8-elem group
    const int row  = gidx >> 6;
    const int c8   = (gidx & 63) * 8;
    const float li = 1.0f / (lP[row] + lP[MTOT + row]);
    const bf16x8 a = *reinterpret_cast<const bf16x8*>(&pO[(size_t)row * 512 + c8]);
    const bf16x8 bvv = *reinterpret_cast<const bf16x8*>(
        &pO[((size_t)MTOT + row) * 512 + c8]);
    bf16x8 r8;
#pragma unroll
    for (int j = 0; j < 8; ++j)
        r8[j] = (__bf16)(((float)a[j] + (float)bvv[j]) * li);
    *reinterpret_cast<bf16x8*>(&att[(size_t)row * 512 + c8]) = r8;
}

// ---------------------------------------------------------------------------
extern "C" void kernel_launch(void* const* d_in, const int* in_sizes, int n_in,
                              void* d_out, int out_size, void* d_ws, size_t ws_size,
                              hipStream_t stream)
{
    (void)in_sizes; (void)n_in; (void)out_size; (void)ws_size;

    const float* x  = (const float*)d_in[0];
    const float* Wq = (const float*)d_in[1];
    const float* bq = (const float*)d_in[2];
    const float* Wk = (const float*)d_in[3];
    const float* bk = (const float*)d_in[4];
    const float* Wv = (const float*)d_in[5];
    const float* bv = (const float*)d_in[6];
    const float* Wo = (const float*)d_in[7];
    const float* bo = (const float*)d_in[8];
    float* out = (float*)d_out;

    // ws (48.1 MB): qb, kb, vbT (16 MB each) + lP. Scratch that is dead by
    // the time its region is overwritten:
    //   xb + WqT/WkT/WvT live in d_out (overwritten by pO during flash)
    //   WoT lives in kb (kb dead after flash)
    //   ab (attended) overlays qb (dead after flash)
    __bf16* qb  = (__bf16*)d_ws;
    __bf16* kb  = qb  + (size_t)MTOT * 512;
    __bf16* vbT = kb  + (size_t)MTOT * 512;
    float*  lP  = (float*)(vbT + (size_t)MTOT * 512);
    __bf16* pO  = (__bf16*)d_out;
    __bf16* ab  = qb;

    __bf16* xb  = (__bf16*)d_out;
    __bf16* WqT = xb  + (size_t)MTOT * 512;
    __bf16* WkT = WqT + 512 * 512;
    __bf16* WvT = WkT + 512 * 512;
    __bf16* WoT = kb;

    prep<<<4288, 256, 0, stream>>>(x, xb, Wq, Wk, Wv, WqT, WkT, WvT);

    qkv_gemm<<<1024, 256, 0, stream>>>(xb, WqT, bq, WkT, bk, WvT, bv, qb, kb, vbT);

    flash_attn<<<256, 512, 0, stream>>>(qb, kb, vbT, pO, lP);

    merge_wo<<<4160, 256, 0, stream>>>(pO, lP, ab, Wo, WoT);

    out_gemm<<<512, 256, 0, stream>>>(ab, WoT, bo, out);
}